// Round 9
// baseline (676.485 us; speedup 1.0000x reference)
//
#include <hip/hip_runtime.h>
#include <math.h>

#define EPSV 1e-5f

typedef __attribute__((ext_vector_type(8))) short bf16x8;
typedef __attribute__((ext_vector_type(4))) float f32x4;
typedef __attribute__((ext_vector_type(8))) unsigned short u16x8;

__device__ inline unsigned short f2bf(float f) {
    unsigned u = __float_as_uint(f);
    unsigned r = (u + 0x7fffu + ((u >> 16) & 1u)) >> 16;
    return (unsigned short)r;
}

__device__ inline float bf2f(unsigned short h) {
    return __uint_as_float(((unsigned)h) << 16);
}

__device__ inline void gload_lds16(const void* g, void* l) {
    __builtin_amdgcn_global_load_lds(
        (const __attribute__((address_space(1))) void*)g,
        (__attribute__((address_space(3))) void*)l, 16, 0, 0);
}

// ---------------- BN over tokens (B,C,N) -> bf16 ----------------
__global__ __launch_bounds__(256) void bn_to_bf16_kernel(
    const float4* __restrict__ x, ushort4* __restrict__ y,
    const float* __restrict__ g, const float* __restrict__ be,
    const float* __restrict__ mu, const float* __restrict__ va)
{
    int i = blockIdx.x * 256 + threadIdx.x;
    int c = (i >> 11) & 255;
    float s = g[c] * rsqrtf(va[c] + EPSV);
    float t = be[c] - mu[c] * s;
    float4 v = x[i];
    ushort4 h;
    h.x = f2bf(v.x * s + t); h.y = f2bf(v.y * s + t);
    h.z = f2bf(v.z * s + t); h.w = f2bf(v.w * s + t);
    y[i] = h;
}

// ---------------- MFMA flatten einsum: single-barrier counted-vmcnt pipeline ----------------
__global__ __launch_bounds__(256) void flatten_gemm_mfma(
    const unsigned short* __restrict__ A, const float* __restrict__ Bm,
    float* __restrict__ Pbase)
{
    __shared__ __align__(16) unsigned short AS[4][256 * 32];
    __shared__ __align__(16) unsigned short BS[4][64 * 32];
    const int NTT = 64;
    int t = threadIdx.x;
    int wid = t >> 6, lane = t & 63;
    int fid = blockIdx.z * 64 + blockIdx.x;
    int nid = (fid & 7) * 64 + (fid >> 3);
    int n0 = (nid & 63) * 64;
    int zz = nid >> 6;
    int ks = zz & 3, b = zz >> 2;
    const unsigned short* Ab = A + b * (256 * 8192);
    const float* Bb = Bm + (long)b * (4096 * 8192) + (long)n0 * 8192;
    int k0 = ks * 2048;
    int brow = t >> 3, bc8 = t & 7;
    int l15 = lane & 15, kc = lane >> 4;

    f32x4 acc[4][4] = {};

    auto issueA = [&](int tile) {
        int buf = tile & 3;
        int kb = k0 + tile * 32;
        #pragma unroll
        for (int j = 0; j < 4; ++j) {
            int d16 = (wid * 4 + j) * 64 + lane;
            int row = d16 >> 2;
            int ch = (d16 & 3) ^ ((row >> 1) & 3);
            gload_lds16(Ab + row * 8192 + kb + ch * 8, &AS[buf][(wid * 4 + j) * 512]);
        }
    };
    auto loadB = [&](int tile, float4& f0, float4& f1) {
        int kb = k0 + tile * 32;
        f0 = *(const float4*)(Bb + brow * 8192 + kb + bc8 * 4);
        f1 = *(const float4*)(Bb + (brow + 32) * 8192 + kb + bc8 * 4);
    };
    auto writeB = [&](int tile, const float4& f0, const float4& f1) {
        int buf = tile & 3;
        int ch16 = (bc8 >> 1) ^ ((brow >> 1) & 3);
        ushort4 h;
        h.x = f2bf(f0.x); h.y = f2bf(f0.y); h.z = f2bf(f0.z); h.w = f2bf(f0.w);
        *reinterpret_cast<ushort4*>(&BS[buf][brow * 32 + ch16 * 8 + (bc8 & 1) * 4]) = h;
        int rr2 = brow + 32;
        int ch16b = (bc8 >> 1) ^ ((rr2 >> 1) & 3);
        ushort4 h2;
        h2.x = f2bf(f1.x); h2.y = f2bf(f1.y); h2.z = f2bf(f1.z); h2.w = f2bf(f1.w);
        *reinterpret_cast<ushort4*>(&BS[buf][rr2 * 32 + ch16b * 8 + (bc8 & 1) * 4]) = h2;
    };
    auto mmac = [&](int tile) {
        int buf = tile & 3;
        bf16x8 af[4], bfr[4];
        #pragma unroll
        for (int mf = 0; mf < 4; ++mf) {
            int row = wid * 64 + mf * 16 + l15;
            int ch = kc ^ ((row >> 1) & 3);
            af[mf] = *reinterpret_cast<const bf16x8*>(&AS[buf][row * 32 + ch * 8]);
        }
        #pragma unroll
        for (int nf = 0; nf < 4; ++nf) {
            int row = nf * 16 + l15;
            int ch = kc ^ ((row >> 1) & 3);
            bfr[nf] = *reinterpret_cast<const bf16x8*>(&BS[buf][row * 32 + ch * 8]);
        }
        #pragma unroll
        for (int mf = 0; mf < 4; ++mf)
            #pragma unroll
            for (int nf = 0; nf < 4; ++nf)
                acc[mf][nf] = __builtin_amdgcn_mfma_f32_16x16x32_bf16(
                    af[mf], bfr[nf], acc[mf][nf], 0, 0, 0);
    };

    float4 q00, q01, q10, q11, r0, r1;
    loadB(0, q00, q01);
    loadB(1, q10, q11);
    issueA(0);
    issueA(1);

    for (int tau = 0; tau < NTT; ++tau) {
        writeB(tau, q00, q01);
        if (tau == 0)
            asm volatile("s_waitcnt vmcnt(4) lgkmcnt(0)" ::: "memory");
        else if (tau < NTT - 1)
            asm volatile("s_waitcnt vmcnt(6) lgkmcnt(0)" ::: "memory");
        else
            asm volatile("s_waitcnt vmcnt(0) lgkmcnt(0)" ::: "memory");
        __builtin_amdgcn_s_barrier();
        if (tau + 2 < NTT) {
            loadB(tau + 2, r0, r1);
            issueA(tau + 2);
        }
        mmac(tau);
        q00 = q10; q01 = q11; q10 = r0; q11 = r1;
    }

    float* P = Pbase + (long)ks * 2097152;
    float* Cb = P + (b * 256) * 4096 + n0;
    #pragma unroll
    for (int mf = 0; mf < 4; ++mf) {
        int rbase = wid * 64 + mf * 16 + (lane >> 4) * 4;
        #pragma unroll
        for (int nf = 0; nf < 4; ++nf) {
            int col = nf * 16 + (lane & 15);
            #pragma unroll
            for (int r = 0; r < 4; ++r)
                Cb[(rbase + r) * 4096 + col] = acc[mf][nf][r];
        }
    }
}

// ---------------- add4 + transpose -> rgrid_bf bf16 (p,c) ----------------
__global__ __launch_bounds__(256) void add4_t_kernel(
    const float* __restrict__ p, unsigned short* __restrict__ obf)
{
    __shared__ float tl[64][65];
    int t = threadIdx.x;
    int b = blockIdx.z;
    int c0 = blockIdx.y * 64, p0 = blockIdx.x * 64;
    #pragma unroll
    for (int u = 0; u < 16; ++u) {
        int idx = u * 256 + t;
        int cl = idx >> 6, pl = idx & 63;
        long g = (long)(b * 256 + c0 + cl) * 4096 + p0 + pl;
        tl[cl][pl] = p[g] + p[g + 2097152] + p[g + 2 * 2097152] + p[g + 3 * 2097152];
    }
    __syncthreads();
    #pragma unroll
    for (int u = 0; u < 16; ++u) {
        int idx = u * 256 + t;
        int pl = idx >> 6, cl = idx & 63;
        obf[(long)(b * 4096 + p0 + pl) * 256 + c0 + cl] = f2bf(tl[cl][pl]);
    }
}

// ---------------- weight pack for convT: wp[par][tap][o][c] bf16 ----------------
__global__ __launch_bounds__(256) void wpack_kernel(
    const float* __restrict__ w, unsigned short* __restrict__ wp, int Cout, int Cin)
{
    int id = blockIdx.x * 256 + threadIdx.x;
    int nc8 = Cin >> 3;
    int cch = id % nc8;
    int rest = id / nc8;
    int o = rest % Cout;
    int pt = rest / Cout;
    if (pt >= 16) return;
    int par = pt >> 2, tap = pt & 3;
    int py = par >> 1, px = par & 1, u = tap >> 1, v = tap & 1;
    int tf = (3 - py - 2 * u) * 4 + (3 - px - 2 * v);
    u16x8 h;
    #pragma unroll
    for (int e = 0; e < 8; ++e)
        h[e] = f2bf(w[((cch * 8 + e) * Cout + o) * 16 + tf]);
    *reinterpret_cast<u16x8*>(&wp[((pt * Cout + o) * Cin) + cch * 8]) = h;
}

// ---------------- generic 1x1 conv via MFMA, templated N-tile ----------------
template<int NF>
__global__ __launch_bounds__(256) void conv1x1_mfma(
    const unsigned short* __restrict__ xbf, const float* __restrict__ w,
    const float* __restrict__ bias, float* __restrict__ of32,
    unsigned short* __restrict__ obf, int Cin, int Cout, int P, int act)
{
    constexpr int BP = NF * 64;
    __shared__ __align__(16) unsigned short XS[2][BP * 32];
    __shared__ __align__(16) unsigned short WS[2][64 * 32];
    int t = threadIdx.x;
    int wid = t >> 6, lane = t & 63;
    int b = blockIdx.z;
    int p0 = blockIdx.x * BP, o0 = blockIdx.y * 64;
    const unsigned short* xb = xbf + (long)b * P * Cin;
    int wm = t >> 2, wq = t & 3;
    int chunks = Cin >> 5;

    f32x4 acc[4][NF] = {};

    #pragma unroll
    for (int j = 0; j < NF; ++j) {
        int d16 = (wid * NF + j) * 64 + lane;
        int p = d16 >> 2;
        int ch = (d16 & 3) ^ ((p >> 1) & 3);
        gload_lds16(xb + (long)(p0 + p) * Cin + ch * 8, &XS[0][(wid * NF + j) * 512]);
    }
    float4 wr0 = *(const float4*)(w + (o0 + wm) * Cin + wq * 8);
    float4 wr1 = *(const float4*)(w + (o0 + wm) * Cin + wq * 8 + 4);
    __syncthreads();

    for (int cc = 0; cc < chunks; ++cc) {
        int cur = cc & 1;
        {
            int chq = wq ^ ((wm >> 1) & 3);
            u16x8 h;
            h[0] = f2bf(wr0.x); h[1] = f2bf(wr0.y); h[2] = f2bf(wr0.z); h[3] = f2bf(wr0.w);
            h[4] = f2bf(wr1.x); h[5] = f2bf(wr1.y); h[6] = f2bf(wr1.z); h[7] = f2bf(wr1.w);
            *reinterpret_cast<u16x8*>(&WS[cur][wm * 32 + chq * 8]) = h;
        }
        __syncthreads();

        if (cc < chunks - 1) {
            int kn = (cc + 1) * 32;
            #pragma unroll
            for (int j = 0; j < NF; ++j) {
                int d16 = (wid * NF + j) * 64 + lane;
                int p = d16 >> 2;
                int ch = (d16 & 3) ^ ((p >> 1) & 3);
                gload_lds16(xb + (long)(p0 + p) * Cin + kn + ch * 8,
                            &XS[cur ^ 1][(wid * NF + j) * 512]);
            }
            wr0 = *(const float4*)(w + (o0 + wm) * Cin + kn + wq * 8);
            wr1 = *(const float4*)(w + (o0 + wm) * Cin + kn + wq * 8 + 4);
        }

        int l15 = lane & 15, kc = lane >> 4;
        bf16x8 af[4], bfr[NF];
        #pragma unroll
        for (int mf = 0; mf < 4; ++mf) {
            int row = mf * 16 + l15;
            int ch = kc ^ ((row >> 1) & 3);
            af[mf] = *reinterpret_cast<const bf16x8*>(&WS[cur][row * 32 + ch * 8]);
        }
        #pragma unroll
        for (int nf = 0; nf < NF; ++nf) {
            int row = wid * (NF * 16) + nf * 16 + l15;
            int ch = kc ^ ((row >> 1) & 3);
            bfr[nf] = *reinterpret_cast<const bf16x8*>(&XS[cur][row * 32 + ch * 8]);
        }
        #pragma unroll
        for (int mf = 0; mf < 4; ++mf)
            #pragma unroll
            for (int nf = 0; nf < NF; ++nf)
                acc[mf][nf] = __builtin_amdgcn_mfma_f32_16x16x32_bf16(
                    af[mf], bfr[nf], acc[mf][nf], 0, 0, 0);
        __syncthreads();
    }

    int l15 = lane & 15, kc4 = lane >> 4;
    #pragma unroll
    for (int mf = 0; mf < 4; ++mf) {
        #pragma unroll
        for (int nf = 0; nf < NF; ++nf) {
            int p = wid * (NF * 16) + nf * 16 + l15;
            ushort4 hb;
            #pragma unroll
            for (int r = 0; r < 4; ++r) {
                int m = mf * 16 + kc4 * 4 + r;
                float v = acc[mf][nf][r] + bias[o0 + m];
                if (act == 1) v = fmaxf(v, 0.f);
                else if (act == 2) v = 0.5f * v * (1.f + erff(v * 0.70710678118f));
                if (of32) of32[((long)(b * Cout) + o0 + m) * P + p0 + p] = v;
                ((unsigned short*)&hb)[r] = f2bf(v);
            }
            if (obf)
                *reinterpret_cast<ushort4*>(
                    &obf[(long)(b * P + p0 + p) * Cout + o0 + mf * 16 + kc4 * 4]) = hb;
        }
    }
}

// ---------------- ConvTranspose2d(k=4,s=2,p=1) via MFMA parity decomposition ----------------
__global__ __launch_bounds__(256) void convt_mfma(
    const unsigned short* __restrict__ xbf, const unsigned short* __restrict__ wp,
    const float* __restrict__ bias, const float* __restrict__ g,
    const float* __restrict__ be, const float* __restrict__ mu,
    const float* __restrict__ va, const unsigned short* __restrict__ resbf,
    float* __restrict__ of32, unsigned short* __restrict__ obf,
    int Cin, int Cout, int Hin, int Win, int TR, int cshift, int OCtot, int cof)
{
    __shared__ __align__(16) unsigned short XS[165 * 32];
    __shared__ __align__(16) unsigned short WS[4 * 64 * 32];
    int t = threadIdx.x;
    int wid = t >> 6, lane = t & 63;
    int z = blockIdx.z;
    int b = z >> 2, par = z & 3;
    int py = par >> 1, px = par & 1;
    int o0 = blockIdx.y * 64;
    int i0 = blockIdx.x * TR;
    int CW = Win, CW1 = CW + 1;
    int npatch = (TR + 1) * CW1;
    int Pin = Hin * Win, Pout = 4 * Hin * Win;
    const unsigned short* xb = xbf + (long)b * Pin * Cin;
    int chunks = Cin >> 5;
    int l15 = lane & 15, kc = lane >> 4;

    f32x4 acc[4][2] = {};

    for (int cc = 0; cc < chunks; ++cc) {
        __syncthreads();
        for (int idx = t; idx < npatch * 4; idx += 256) {
            int pp = idx >> 2, ql = idx & 3;
            int qs = ql ^ ((pp >> 1) & 3);
            int a = pp / CW1, bcol = pp - a * CW1;
            int iy = i0 - (1 - py) + a;
            int ix = bcol - (1 - px);
            u16x8 v = {};
            if (iy >= 0 && iy < Hin && ix >= 0 && ix < Win)
                v = *reinterpret_cast<const u16x8*>(
                    &xb[(long)(iy * Win + ix) * Cin + cc * 32 + qs * 8]);
            *reinterpret_cast<u16x8*>(&XS[pp * 32 + ql * 8]) = v;
        }
        {
            int m = t >> 2, q = t & 3;
            int chq = q ^ ((m >> 1) & 3);
            #pragma unroll
            for (int tap = 0; tap < 4; ++tap) {
                u16x8 v = *reinterpret_cast<const u16x8*>(
                    &wp[((long)((par * 4 + tap) * Cout + o0 + m)) * Cin + cc * 32 + q * 8]);
                *reinterpret_cast<u16x8*>(&WS[tap * 2048 + m * 32 + chq * 8]) = v;
            }
        }
        __syncthreads();

        #pragma unroll
        for (int tap = 0; tap < 4; ++tap) {
            int u = tap >> 1, v = tap & 1;
            bf16x8 af[4], bfr[2];
            #pragma unroll
            for (int mf = 0; mf < 4; ++mf) {
                int row = mf * 16 + l15;
                int ch = kc ^ ((row >> 1) & 3);
                af[mf] = *reinterpret_cast<const bf16x8*>(&WS[tap * 2048 + row * 32 + ch * 8]);
            }
            #pragma unroll
            for (int nf = 0; nf < 2; ++nf) {
                int n = wid * 32 + nf * 16 + l15;
                int rn = n >> cshift, cn = n & (CW - 1);
                int pp = (rn + u) * CW1 + cn + v;
                int ch = kc ^ ((pp >> 1) & 3);
                bfr[nf] = *reinterpret_cast<const bf16x8*>(&XS[pp * 32 + ch * 8]);
            }
            #pragma unroll
            for (int mf = 0; mf < 4; ++mf)
                #pragma unroll
                for (int nf = 0; nf < 2; ++nf)
                    acc[mf][nf] = __builtin_amdgcn_mfma_f32_16x16x32_bf16(
                        af[mf], bfr[nf], acc[mf][nf], 0, 0, 0);
        }
    }

    int kc4 = lane >> 4;
    #pragma unroll
    for (int nf = 0; nf < 2; ++nf) {
        int n = wid * 32 + nf * 16 + l15;
        int rn = n >> cshift, cn = n & (CW - 1);
        int y = 2 * (i0 + rn) + py;
        int xx = 2 * cn + px;
        int pout = y * 2 * Win + xx;
        #pragma unroll
        for (int mf = 0; mf < 4; ++mf) {
            ushort4 hb;
            #pragma unroll
            for (int r = 0; r < 4; ++r) {
                int m = mf * 16 + kc4 * 4 + r;
                int o = o0 + m;
                float s = g[o] * rsqrtf(va[o] + EPSV);
                float v = (acc[mf][nf][r] + bias[o]) * s + (be[o] - mu[o] * s);
                if (resbf) v += bf2f(resbf[(long)(b * Pout + pout) * 256 + o]);
                if (of32) of32[((long)(b * Cout) + o) * Pout + pout] = v;
                ((unsigned short*)&hb)[r] = f2bf(v);
            }
            if (obf)
                *reinterpret_cast<ushort4*>(
                    &obf[(long)(b * Pout + pout) * OCtot + cof + o0 + mf * 16 + kc4 * 4]) = hb;
        }
    }
}

// ---------------- fused lifting PAIR: d = xO - tanh(netP(xE)); c = xE + tanh(netU(d)) ----------------
// Block owns complete conv-lines (rows or cols) for all 64 channels; d stays in LDS.
// 1024 thr = 64 px x 16 wave-uniform oc-groups; scalar weight loads.
__global__ __launch_bounds__(1024) void lift_pair_kernel(
    const float* __restrict__ xA, const float* __restrict__ xB,
    float* __restrict__ dA, float* __restrict__ dB,
    float* __restrict__ cA, float* __restrict__ cB,
    int x_sB, int x_sC, int x_sR, int x_sA, int x_odd,
    int u_sB, int u_sC, int u_sR, int u_sA,
    const float* __restrict__ w1P, const float* __restrict__ b1P,
    const float* __restrict__ w2P, const float* __restrict__ b2P,
    const float* __restrict__ w1U, const float* __restrict__ b1U,
    const float* __restrict__ w2U, const float* __restrict__ b2U,
    int L, int lsh,
    unsigned short* __restrict__ obf, int Pb, int OCb,
    int cofDA, int cofCA, int cofDB, int cofCB)
{
    __shared__ float xsmE[4864];   // 64c * rpb * (L+3), reflect-padded even
    __shared__ float xsmO[4096];   // 64c * rpb * L, odd
    __shared__ float xsmD[4864];   // padded d
    __shared__ float hsm[8192];    // 128h x 64px
    int t = threadIdx.x;
    int g = t & 63, ocg = t >> 6;
    int b = blockIdx.z;
    int sel = blockIdx.y;
    const float* xin = sel ? xB : xA;
    float* dout = sel ? dB : dA;
    float* cout_ = sel ? cB : cA;
    int cofD = sel ? cofDB : cofDA;
    int cofC = sel ? cofCB : cofCA;
    int rpb = 64 >> lsh;
    int row0 = blockIdx.x * rpb;
    int Lp = L + 3;
    // ---- stage even (padded) + odd ----
    int totalE = 64 * rpb * Lp;
    for (int idx = t; idx < totalE; idx += 1024) {
        int c = idx / (rpb * Lp);
        int rem = idx - c * rpb * Lp;
        int r = rem / Lp;
        int q = rem - r * Lp;
        int s = q - 2;
        s = (s < 0) ? -s : s;
        if (s >= L) s = 2 * L - 2 - s;
        xsmE[idx] = xin[b * x_sB + c * x_sC + (row0 + r) * x_sR + s * x_sA];
    }
    int totalO = 64 * rpb * L;
    for (int idx = t; idx < totalO; idx += 1024) {
        int c = idx / (rpb * L);
        int rem = idx - c * rpb * L;
        int r = rem / L;
        int j = rem - r * L;
        xsmO[idx] = xin[b * x_sB + c * x_sC + (row0 + r) * x_sR + j * x_sA + x_odd];
    }
    __syncthreads();

    int ocgu = __builtin_amdgcn_readfirstlane(ocg);
    int rl = g >> lsh, jl = g & (L - 1);
    int rg = row0 + rl;
    int p = rg * u_sR + jl * u_sA;

    // ================= phase P =================
    {
        const float* w1u = w1P + ocgu * 8 * 256;
        float acc1[8] = {};
        for (int c = 0; c < 64; ++c) {
            const float* xr = &xsmE[(c * rpb + rl) * Lp + jl];
            float x0 = xr[0], x1 = xr[1], x2 = xr[2], x3 = xr[3];
            const float* wc = w1u + c * 4;
            #pragma unroll
            for (int k = 0; k < 8; ++k) {
                const float* wr = wc + k * 256;
                acc1[k] += wr[0] * x0 + wr[1] * x1 + wr[2] * x2 + wr[3] * x3;
            }
        }
        #pragma unroll
        for (int k = 0; k < 8; ++k) {
            int oc = ocgu * 8 + k;
            hsm[oc * 64 + g] = fmaxf(acc1[k] + b1P[oc], 0.f);
        }
        __syncthreads();
        const float* w2u = w2P + ocgu * 4 * 128;
        float acc2[4] = {};
        for (int h4 = 0; h4 < 32; ++h4) {
            float hv0 = hsm[(h4 * 4 + 0) * 64 + g];
            float hv1 = hsm[(h4 * 4 + 1) * 64 + g];
            float hv2 = hsm[(h4 * 4 + 2) * 64 + g];
            float hv3 = hsm[(h4 * 4 + 3) * 64 + g];
            #pragma unroll
            for (int kk = 0; kk < 4; ++kk) {
                const float* wr = w2u + kk * 128 + h4 * 4;
                acc2[kk] += wr[0] * hv0 + wr[1] * hv1 + wr[2] * hv2 + wr[3] * hv3;
            }
        }
        #pragma unroll
        for (int kk = 0; kk < 4; ++kk) {
            int o = ocgu * 4 + kk;
            float v = xsmO[(o * rpb + rl) * L + jl] - tanhf(acc2[kk] + b2P[o]);
            dout[b * u_sB + o * u_sC + p] = v;
            xsmD[(o * rpb + rl) * Lp + jl + 2] = v;
            if (obf && cofD >= 0) obf[(long)(b * Pb + p) * OCb + cofD + o] = f2bf(v);
        }
    }
    __syncthreads();
    // fill reflect pads of xsmD: q0<-interior(4), q1<-interior(3), qL+2<-interior(L)
    for (int idx = t; idx < 64 * rpb; idx += 1024) {
        float* base = &xsmD[idx * Lp];
        base[0] = base[4];
        base[1] = base[3];
        base[L + 2] = base[L];
    }
    __syncthreads();

    // ================= phase U =================
    {
        const float* w1u = w1U + ocgu * 8 * 256;
        float acc1[8] = {};
        for (int c = 0; c < 64; ++c) {
            const float* xr = &xsmD[(c * rpb + rl) * Lp + jl];
            float x0 = xr[0], x1 = xr[1], x2 = xr[2], x3 = xr[3];
            const float* wc = w1u + c * 4;
            #pragma unroll
            for (int k = 0; k < 8; ++k) {
                const float* wr = wc + k * 256;
                acc1[k] += wr[0] * x0 + wr[1] * x1 + wr[2] * x2 + wr[3] * x3;
            }
        }
        __syncthreads();   // hsm reuse: previous reads done (pad-fill barrier passed, but be safe)
        #pragma unroll
        for (int k = 0; k < 8; ++k) {
            int oc = ocgu * 8 + k;
            hsm[oc * 64 + g] = fmaxf(acc1[k] + b1U[oc], 0.f);
        }
        __syncthreads();
        const float* w2u = w2U + ocgu * 4 * 128;
        float acc2[4] = {};
        for (int h4 = 0; h4 < 32; ++h4) {
            float hv0 = hsm[(h4 * 4 + 0) * 64 + g];
            float hv1 = hsm[(h4 * 4 + 1) * 64 + g];
            float hv2 = hsm[(h4 * 4 + 2) * 64 + g];
            float hv3 = hsm[(h4 * 4 + 3) * 64 + g];
            #pragma unroll
            for (int kk = 0; kk < 4; ++kk) {
                const float* wr = w2u + kk * 128 + h4 * 4;
                acc2[kk] += wr[0] * hv0 + wr[1] * hv1 + wr[2] * hv2 + wr[3] * hv3;
            }
        }
        #pragma unroll
        for (int kk = 0; kk < 4; ++kk) {
            int o = ocgu * 4 + kk;
            float v = xsmE[(o * rpb + rl) * Lp + jl + 2] + tanhf(acc2[kk] + b2U[o]);
            cout_[b * u_sB + o * u_sC + p] = v;
            if (obf && cofC >= 0) obf[(long)(b * Pb + p) * OCb + cofC + o] = f2bf(v);
        }
    }
}

// ---------------- fused dw3x3 + relu + dw3x3 + scale + inflate gather + residual ----------------
__global__ __launch_bounds__(256) void dw_fused_kernel(
    const float* __restrict__ r2, const float* __restrict__ w1, const float* __restrict__ b1,
    const float* __restrict__ w2, const float* __restrict__ b2v,
    const float* __restrict__ scw, const float* __restrict__ tok,
    const int* __restrict__ idx, float* __restrict__ out)
{
    __shared__ float s0[64][68];
    __shared__ float s1[64][68];
    __shared__ float s2[4096];
    int bc = blockIdx.x;
    int c = bc & 255;
    int t = threadIdx.x;
    const float* xp = r2 + (long)bc * 4096;
    for (int i = t; i < 4096; i += 256) s0[i >> 6][i & 63] = xp[i];
    float wa[9], wb[9];
    #pragma unroll
    for (int k = 0; k < 9; ++k) { wa[k] = w1[c * 9 + k]; wb[k] = w2[c * 9 + k]; }
    float ba = b1[c], bb = b2v[c], sc = scw[c];
    __syncthreads();
    for (int i = t; i < 4096; i += 256) {
        int y = i >> 6, x = i & 63;
        float a = ba;
        #pragma unroll
        for (int ky = 0; ky < 3; ++ky) {
            int yy = y + ky - 1;
            if (yy < 0 || yy > 63) continue;
            #pragma unroll
            for (int kx = 0; kx < 3; ++kx) {
                int xx = x + kx - 1;
                if (xx < 0 || xx > 63) continue;
                a += wa[ky * 3 + kx] * s0[yy][xx];
            }
        }
        s1[y][x] = fmaxf(a, 0.f);
    }
    __syncthreads();
    for (int i = t; i < 4096; i += 256) {
        int y = i >> 6, x = i & 63;
        float a = bb;
        #pragma unroll
        for (int ky = 0; ky < 3; ++ky) {
            int yy = y + ky - 1;
            if (yy < 0 || yy > 63) continue;
            #pragma unroll
            for (int kx = 0; kx < 3; ++kx) {
                int xx = x + kx - 1;
                if (xx < 0 || xx > 63) continue;
                a += wb[ky * 3 + kx] * s1[yy][xx];
            }
        }
        s2[i] = a * sc;
    }
    __syncthreads();
    long base = (long)bc << 13;
    const int4* ip = (const int4*)(idx + base);
    const float4* tp = (const float4*)(tok + base);
    float4* op = (float4*)(out + base);
    for (int i = t; i < 2048; i += 256) {
        int4 iv = ip[i];
        float4 tv = tp[i];
        float4 o;
        o.x = tv.x + s2[iv.x];
        o.y = tv.y + s2[iv.y];
        o.z = tv.z + s2[iv.z];
        o.w = tv.w + s2[iv.w];
        op[i] = o;
    }
}

extern "C" void kernel_launch(void* const* d_in, const int* in_sizes, int n_in,
                              void* d_out, int out_size, void* d_ws, size_t ws_size,
                              hipStream_t stream)
{
    const float* tokens = (const float*)d_in[0];
    const float* fm     = (const float*)d_in[1];
    const int*   infl   = (const int*)d_in[2];
    const float* bng = (const float*)d_in[3];
    const float* bnb = (const float*)d_in[4];
    const float* bnm = (const float*)d_in[5];
    const float* bnv = (const float*)d_in[6];
    const float* red_w = (const float*)d_in[7];
    const float* red_b = (const float*)d_in[8];
    const float* lw1 = (const float*)d_in[9];
    const float* lb1 = (const float*)d_in[10];
    const float* lw2 = (const float*)d_in[11];
    const float* lb2 = (const float*)d_in[12];
    const float* f2w1 = (const float*)d_in[13];
    const float* f2b1 = (const float*)d_in[14];
    const float* f2w2 = (const float*)d_in[15];
    const float* f2b2 = (const float*)d_in[16];
    const float* ct2w = (const float*)d_in[17];
    const float* ct2b = (const float*)d_in[18];
    const float* bn2g = (const float*)d_in[19];
    const float* bn2b = (const float*)d_in[20];
    const float* bn2m = (const float*)d_in[21];
    const float* bn2v = (const float*)d_in[22];
    const float* f1w1 = (const float*)d_in[23];
    const float* f1b1 = (const float*)d_in[24];
    const float* f1w2 = (const float*)d_in[25];
    const float* f1b2 = (const float*)d_in[26];
    const float* ct1w = (const float*)d_in[27];
    const float* ct1b = (const float*)d_in[28];
    const float* bn1g = (const float*)d_in[29];
    const float* bn1b = (const float*)d_in[30];
    const float* bn1m = (const float*)d_in[31];
    const float* bn1v = (const float*)d_in[32];
    const float* dw1w = (const float*)d_in[33];
    const float* dw1b = (const float*)d_in[34];
    const float* dw2w = (const float*)d_in[35];
    const float* dw2b = (const float*)d_in[36];
    const float* scw  = (const float*)d_in[37];

    float* ws = (float*)d_ws;
    unsigned short* Abf = (unsigned short*)ws;                    // 2,097,152 fl
    float* part  = ws + 2097152;                                  // 4 x 2,097,152 fl
    unsigned short* rgrid_bf = (unsigned short*)(ws + 10485760);  // 1,048,576 fl
    float* rr    = ws + 11534336;   // 524,288
    float* c1    = ws + 12058624;   // 262,144
    float* d1    = ws + 12320768;   // 262,144
    float* c2    = ws + 12582912;   // 65,536
    float* d2    = ws + 12648448;   // 65,536
    float* x2    = ws + 12713984;   // 131,072
    unsigned short* x2_bf  = (unsigned short*)(ws + 12845056);    // 65,536 fl
    float* x1    = ws + 12910592;   // 786,432
    unsigned short* x1_bf  = (unsigned short*)(ws + 13697024);    // 393,216 fl
    unsigned short* g2_bf  = (unsigned short*)(ws + 14090240);    // 65,536 fl
    unsigned short* y2p_bf = (unsigned short*)(ws + 14155776);    // 65,536 fl
    unsigned short* g1_bf  = (unsigned short*)(ws + 14221312);    // 262,144 fl
    unsigned short* y1p_bf = (unsigned short*)(ws + 14483456);    // 262,144 fl
    unsigned short* wp2    = (unsigned short*)(ws + 14745600);    // 262,144 fl
    unsigned short* wp1    = (unsigned short*)(ws + 15007744);    // 524,288 fl
    float* r2 = ws + 15532032;      // 2,097,152

    // weight packs (independent)
    wpack_kernel<<<512, 256, 0, stream>>>(ct1w, wp1, 256, 256);
    wpack_kernel<<<256, 256, 0, stream>>>(ct2w, wp2, 128, 256);

    // 1. BN -> bf16
    bn_to_bf16_kernel<<<4096, 256, 0, stream>>>((const float4*)tokens, (ushort4*)Abf,
                                                bng, bnb, bnm, bnv);
    // 2. flatten einsum + reduce/transpose
    flatten_gemm_mfma<<<dim3(64, 1, 8), 256, 0, stream>>>(Abf, fm, part);
    add4_t_kernel<<<dim3(64, 4, 2), 256, 0, stream>>>(part, rgrid_bf);
    // 3. reduce 1x1 (256->64), f32 out
    conv1x1_mfma<2><<<dim3(32, 1, 2), 256, 0, stream>>>(rgrid_bf, red_w, red_b,
                                                        rr, (unsigned short*)nullptr,
                                                        256, 64, 4096, 0);

    auto lpair = [&](const float* xA, const float* xB,
                     float* dA, float* dB, float* cA, float* cB,
                     int xsB, int xsC, int xsR, int xsA, int xodd,
                     int usB, int usC, int usR, int usA,
                     int lvl, int sch, int L, int nsel,
                     unsigned short* obf, int Pb, int OCb,
                     int cofDA, int cofCA, int cofDB, int cofCB, int nblk) {
        int wP = (lvl * 2 + sch) * 2;
        int wU = wP + 1;
        int lsh = (L == 32) ? 5 : 4;
        lift_pair_kernel<<<dim3(nblk, nsel, 2), 1024, 0, stream>>>(
            xA, xB, dA, dB, cA, cB,
            xsB, xsC, xsR, xsA, xodd, usB, usC, usR, usA,
            lw1 + wP * 32768, lb1 + wP * 128, lw2 + wP * 8192, lb2 + wP * 64,
            lw1 + wU * 32768, lb1 + wU * 128, lw2 + wU * 8192, lb2 + wU * 64,
            L, lsh, obf, Pb, OCb, cofDA, cofCA, cofDB, cofCB);
    };

    // ---- L1 horizontal pair: rr -> d1, c1 ----
    lpair(rr, rr, d1, d1, c1, c1,
          262144, 4096, 64, 2, 1,  131072, 2048, 32, 1,
          0, 0, 32, 1, nullptr, 0, 0, -1, -1, -1, -1, 32);
    // ---- L1 vertical pair: c1 -> LH1/LL1 ; d1 -> HH1/HL1 (into x1 + x1_bf) ----
    lpair(c1, d1, x1 + 65536, x1 + 196608, x1, x1 + 131072,
          131072, 2048, 1, 64, 32,  393216, 1024, 1, 32,
          0, 1, 32, 2, x1_bf, 1024, 384, 64, 0, 192, 128, 16);
    // ---- L2 horizontal pair on LL1 (view in x1) -> d2, c2 ----
    lpair(x1, x1, d2, d2, c2, c2,
          393216, 1024, 32, 2, 1,  65536, 512, 16, 1,
          1, 0, 16, 1, nullptr, 0, 0, -1, -1, -1, -1, 8);
    // ---- L2 vertical pair: c2 -> LH2/LL2 ; d2 -> HH2/HL2 (into x2 + x2_bf) ----
    lpair(c2, d2, x2 + 16384, x2 + 49152, x2, x2 + 32768,
          65536, 512, 1, 32, 16,  65536, 256, 1, 16,
          1, 1, 16, 2, x2_bf, 256, 256, 64, 0, 192, 128, 4);

    // ---- ff2 (bf16 chain) + ct2 -> x1_bf ch 256..383 ----
    conv1x1_mfma<1><<<dim3(4, 4, 2), 256, 0, stream>>>(x2_bf, f2w1, f2b1,
        (float*)nullptr, g2_bf, 256, 256, 256, 2);
    conv1x1_mfma<1><<<dim3(4, 4, 2), 256, 0, stream>>>(g2_bf, f2w2, f2b2,
        (float*)nullptr, y2p_bf, 256, 256, 256, 0);
    convt_mfma<<<dim3(2, 2, 8), 256, 0, stream>>>(y2p_bf, wp2, ct2b,
        bn2g, bn2b, bn2m, bn2v, (const unsigned short*)nullptr,
        (float*)nullptr, x1_bf, 256, 128, 16, 16, 8, 4, 384, 256);

    // ---- ff1 + ct1 (+res rgrid_bf) -> r2 f32 ----
    conv1x1_mfma<2><<<dim3(8, 4, 2), 256, 0, stream>>>(x1_bf, f1w1, f1b1,
        (float*)nullptr, g1_bf, 384, 256, 1024, 2);
    conv1x1_mfma<2><<<dim3(8, 4, 2), 256, 0, stream>>>(g1_bf, f1w2, f1b2,
        (float*)nullptr, y1p_bf, 256, 256, 1024, 0);
    convt_mfma<<<dim3(8, 4, 8), 256, 0, stream>>>(y1p_bf, wp1, ct1b,
        bn1g, bn1b, bn1m, bn1v, rgrid_bf,
        r2, (unsigned short*)nullptr, 256, 256, 32, 32, 4, 5, 0, 0);

    // ---- fused depthwise x2 + scale + gather + residual ----
    dw_fused_kernel<<<512, 256, 0, stream>>>(r2, dw1w, dw1b, dw2w, dw2b, scw,
                                             tokens, infl, (float*)d_out);
}

// Round 11
// 656.559 us; speedup vs baseline: 1.0303x; 1.0303x over previous
//
#include <hip/hip_runtime.h>
#include <math.h>

#define EPSV 1e-5f

typedef __attribute__((ext_vector_type(8))) short bf16x8;
typedef __attribute__((ext_vector_type(4))) float f32x4;
typedef __attribute__((ext_vector_type(8))) unsigned short u16x8;

__device__ inline unsigned short f2bf(float f) {
    unsigned u = __float_as_uint(f);
    unsigned r = (u + 0x7fffu + ((u >> 16) & 1u)) >> 16;
    return (unsigned short)r;
}

__device__ inline float bf2f(unsigned short h) {
    return __uint_as_float(((unsigned)h) << 16);
}

__device__ inline void gload_lds16(const void* g, void* l) {
    __builtin_amdgcn_global_load_lds(
        (const __attribute__((address_space(1))) void*)g,
        (__attribute__((address_space(3))) void*)l, 16, 0, 0);
}

// ---------------- prep: BN->bf16 (blocks 0..4095) + wpack ct1 (4096..4607) + wpack ct2 (4608..4863) ----------------
__device__ void wpack_item(const float* __restrict__ w, unsigned short* __restrict__ wp,
                           int Cout, int Cin, int id)
{
    int nc8 = Cin >> 3;
    int cch = id % nc8;
    int rest = id / nc8;
    int o = rest % Cout;
    int pt = rest / Cout;
    if (pt >= 16) return;
    int par = pt >> 2, tap = pt & 3;
    int py = par >> 1, px = par & 1, u = tap >> 1, v = tap & 1;
    int tf = (3 - py - 2 * u) * 4 + (3 - px - 2 * v);
    u16x8 h;
    #pragma unroll
    for (int e = 0; e < 8; ++e)
        h[e] = f2bf(w[((cch * 8 + e) * Cout + o) * 16 + tf]);
    *reinterpret_cast<u16x8*>(&wp[((pt * Cout + o) * Cin) + cch * 8]) = h;
}

__global__ __launch_bounds__(256) void prep_kernel(
    const float4* __restrict__ x, ushort4* __restrict__ y,
    const float* __restrict__ g, const float* __restrict__ be,
    const float* __restrict__ mu, const float* __restrict__ va,
    const float* __restrict__ ct1w, unsigned short* __restrict__ wp1,
    const float* __restrict__ ct2w, unsigned short* __restrict__ wp2)
{
    int vb = blockIdx.x, t = threadIdx.x;
    if (vb < 4096) {
        int i = vb * 256 + t;
        int c = (i >> 11) & 255;
        float s = g[c] * rsqrtf(va[c] + EPSV);
        float tt = be[c] - mu[c] * s;
        float4 v = x[i];
        ushort4 h;
        h.x = f2bf(v.x * s + tt); h.y = f2bf(v.y * s + tt);
        h.z = f2bf(v.z * s + tt); h.w = f2bf(v.w * s + tt);
        y[i] = h;
    } else if (vb < 4608) {
        wpack_item(ct1w, wp1, 256, 256, (vb - 4096) * 256 + t);
    } else {
        wpack_item(ct2w, wp2, 128, 256, (vb - 4608) * 256 + t);
    }
}

// ---------------- MFMA flatten einsum: single-barrier counted-vmcnt pipeline ----------------
__global__ __launch_bounds__(256) void flatten_gemm_mfma(
    const unsigned short* __restrict__ A, const float* __restrict__ Bm,
    float* __restrict__ Pbase)
{
    __shared__ __align__(16) unsigned short AS[4][256 * 32];
    __shared__ __align__(16) unsigned short BS[4][64 * 32];
    const int NTT = 64;
    int t = threadIdx.x;
    int wid = t >> 6, lane = t & 63;
    int fid = blockIdx.z * 64 + blockIdx.x;
    int nid = (fid & 7) * 64 + (fid >> 3);
    int n0 = (nid & 63) * 64;
    int zz = nid >> 6;
    int ks = zz & 3, b = zz >> 2;
    const unsigned short* Ab = A + b * (256 * 8192);
    const float* Bb = Bm + (long)b * (4096 * 8192) + (long)n0 * 8192;
    int k0 = ks * 2048;
    int brow = t >> 3, bc8 = t & 7;
    int l15 = lane & 15, kc = lane >> 4;

    f32x4 acc[4][4] = {};

    auto issueA = [&](int tile) {
        int buf = tile & 3;
        int kb = k0 + tile * 32;
        #pragma unroll
        for (int j = 0; j < 4; ++j) {
            int d16 = (wid * 4 + j) * 64 + lane;
            int row = d16 >> 2;
            int ch = (d16 & 3) ^ ((row >> 1) & 3);
            gload_lds16(Ab + row * 8192 + kb + ch * 8, &AS[buf][(wid * 4 + j) * 512]);
        }
    };
    auto loadB = [&](int tile, float4& f0, float4& f1) {
        int kb = k0 + tile * 32;
        f0 = *(const float4*)(Bb + brow * 8192 + kb + bc8 * 4);
        f1 = *(const float4*)(Bb + (brow + 32) * 8192 + kb + bc8 * 4);
    };
    auto writeB = [&](int tile, const float4& f0, const float4& f1) {
        int buf = tile & 3;
        int ch16 = (bc8 >> 1) ^ ((brow >> 1) & 3);
        ushort4 h;
        h.x = f2bf(f0.x); h.y = f2bf(f0.y); h.z = f2bf(f0.z); h.w = f2bf(f0.w);
        *reinterpret_cast<ushort4*>(&BS[buf][brow * 32 + ch16 * 8 + (bc8 & 1) * 4]) = h;
        int rr2 = brow + 32;
        int ch16b = (bc8 >> 1) ^ ((rr2 >> 1) & 3);
        ushort4 h2;
        h2.x = f2bf(f1.x); h2.y = f2bf(f1.y); h2.z = f2bf(f1.z); h2.w = f2bf(f1.w);
        *reinterpret_cast<ushort4*>(&BS[buf][rr2 * 32 + ch16b * 8 + (bc8 & 1) * 4]) = h2;
    };
    auto mmac = [&](int tile) {
        int buf = tile & 3;
        bf16x8 af[4], bfr[4];
        #pragma unroll
        for (int mf = 0; mf < 4; ++mf) {
            int row = wid * 64 + mf * 16 + l15;
            int ch = kc ^ ((row >> 1) & 3);
            af[mf] = *reinterpret_cast<const bf16x8*>(&AS[buf][row * 32 + ch * 8]);
        }
        #pragma unroll
        for (int nf = 0; nf < 4; ++nf) {
            int row = nf * 16 + l15;
            int ch = kc ^ ((row >> 1) & 3);
            bfr[nf] = *reinterpret_cast<const bf16x8*>(&BS[buf][row * 32 + ch * 8]);
        }
        #pragma unroll
        for (int mf = 0; mf < 4; ++mf)
            #pragma unroll
            for (int nf = 0; nf < 4; ++nf)
                acc[mf][nf] = __builtin_amdgcn_mfma_f32_16x16x32_bf16(
                    af[mf], bfr[nf], acc[mf][nf], 0, 0, 0);
    };

    float4 q00, q01, q10, q11, r0, r1;
    loadB(0, q00, q01);
    loadB(1, q10, q11);
    issueA(0);
    issueA(1);

    for (int tau = 0; tau < NTT; ++tau) {
        writeB(tau, q00, q01);
        if (tau == 0)
            asm volatile("s_waitcnt vmcnt(4) lgkmcnt(0)" ::: "memory");
        else if (tau < NTT - 1)
            asm volatile("s_waitcnt vmcnt(6) lgkmcnt(0)" ::: "memory");
        else
            asm volatile("s_waitcnt vmcnt(0) lgkmcnt(0)" ::: "memory");
        __builtin_amdgcn_s_barrier();
        if (tau + 2 < NTT) {
            loadB(tau + 2, r0, r1);
            issueA(tau + 2);
        }
        mmac(tau);
        q00 = q10; q01 = q11; q10 = r0; q11 = r1;
    }

    float* P = Pbase + (long)ks * 2097152;
    float* Cb = P + (b * 256) * 4096 + n0;
    #pragma unroll
    for (int mf = 0; mf < 4; ++mf) {
        int rbase = wid * 64 + mf * 16 + (lane >> 4) * 4;
        #pragma unroll
        for (int nf = 0; nf < 4; ++nf) {
            int col = nf * 16 + (lane & 15);
            #pragma unroll
            for (int r = 0; r < 4; ++r)
                Cb[(rbase + r) * 4096 + col] = acc[mf][nf][r];
        }
    }
}

// ---------------- add4 + transpose -> rgrid_bf bf16 (p,c) ----------------
__global__ __launch_bounds__(256) void add4_t_kernel(
    const float* __restrict__ p, unsigned short* __restrict__ obf)
{
    __shared__ float tl[64][65];
    int t = threadIdx.x;
    int b = blockIdx.z;
    int c0 = blockIdx.y * 64, p0 = blockIdx.x * 64;
    #pragma unroll
    for (int u = 0; u < 16; ++u) {
        int idx = u * 256 + t;
        int cl = idx >> 6, pl = idx & 63;
        long g = (long)(b * 256 + c0 + cl) * 4096 + p0 + pl;
        tl[cl][pl] = p[g] + p[g + 2097152] + p[g + 2 * 2097152] + p[g + 3 * 2097152];
    }
    __syncthreads();
    #pragma unroll
    for (int u = 0; u < 16; ++u) {
        int idx = u * 256 + t;
        int pl = idx >> 6, cl = idx & 63;
        obf[(long)(b * 4096 + p0 + pl) * 256 + c0 + cl] = f2bf(tl[cl][pl]);
    }
}

// ---------------- generic 1x1 conv via MFMA, templated N-tile ----------------
template<int NF>
__global__ __launch_bounds__(256) void conv1x1_mfma(
    const unsigned short* __restrict__ xbf, const float* __restrict__ w,
    const float* __restrict__ bias, float* __restrict__ of32,
    unsigned short* __restrict__ obf, int Cin, int Cout, int P, int act)
{
    constexpr int BP = NF * 64;
    __shared__ __align__(16) unsigned short XS[2][BP * 32];
    __shared__ __align__(16) unsigned short WS[2][64 * 32];
    int t = threadIdx.x;
    int wid = t >> 6, lane = t & 63;
    int b = blockIdx.z;
    int p0 = blockIdx.x * BP, o0 = blockIdx.y * 64;
    const unsigned short* xb = xbf + (long)b * P * Cin;
    int wm = t >> 2, wq = t & 3;
    int chunks = Cin >> 5;

    f32x4 acc[4][NF] = {};

    #pragma unroll
    for (int j = 0; j < NF; ++j) {
        int d16 = (wid * NF + j) * 64 + lane;
        int p = d16 >> 2;
        int ch = (d16 & 3) ^ ((p >> 1) & 3);
        gload_lds16(xb + (long)(p0 + p) * Cin + ch * 8, &XS[0][(wid * NF + j) * 512]);
    }
    float4 wr0 = *(const float4*)(w + (o0 + wm) * Cin + wq * 8);
    float4 wr1 = *(const float4*)(w + (o0 + wm) * Cin + wq * 8 + 4);
    __syncthreads();

    for (int cc = 0; cc < chunks; ++cc) {
        int cur = cc & 1;
        {
            int chq = wq ^ ((wm >> 1) & 3);
            u16x8 h;
            h[0] = f2bf(wr0.x); h[1] = f2bf(wr0.y); h[2] = f2bf(wr0.z); h[3] = f2bf(wr0.w);
            h[4] = f2bf(wr1.x); h[5] = f2bf(wr1.y); h[6] = f2bf(wr1.z); h[7] = f2bf(wr1.w);
            *reinterpret_cast<u16x8*>(&WS[cur][wm * 32 + chq * 8]) = h;
        }
        __syncthreads();

        if (cc < chunks - 1) {
            int kn = (cc + 1) * 32;
            #pragma unroll
            for (int j = 0; j < NF; ++j) {
                int d16 = (wid * NF + j) * 64 + lane;
                int p = d16 >> 2;
                int ch = (d16 & 3) ^ ((p >> 1) & 3);
                gload_lds16(xb + (long)(p0 + p) * Cin + kn + ch * 8,
                            &XS[cur ^ 1][(wid * NF + j) * 512]);
            }
            wr0 = *(const float4*)(w + (o0 + wm) * Cin + kn + wq * 8);
            wr1 = *(const float4*)(w + (o0 + wm) * Cin + kn + wq * 8 + 4);
        }

        int l15 = lane & 15, kc = lane >> 4;
        bf16x8 af[4], bfr[NF];
        #pragma unroll
        for (int mf = 0; mf < 4; ++mf) {
            int row = mf * 16 + l15;
            int ch = kc ^ ((row >> 1) & 3);
            af[mf] = *reinterpret_cast<const bf16x8*>(&WS[cur][row * 32 + ch * 8]);
        }
        #pragma unroll
        for (int nf = 0; nf < NF; ++nf) {
            int row = wid * (NF * 16) + nf * 16 + l15;
            int ch = kc ^ ((row >> 1) & 3);
            bfr[nf] = *reinterpret_cast<const bf16x8*>(&XS[cur][row * 32 + ch * 8]);
        }
        #pragma unroll
        for (int mf = 0; mf < 4; ++mf)
            #pragma unroll
            for (int nf = 0; nf < NF; ++nf)
                acc[mf][nf] = __builtin_amdgcn_mfma_f32_16x16x32_bf16(
                    af[mf], bfr[nf], acc[mf][nf], 0, 0, 0);
        __syncthreads();
    }

    int l15 = lane & 15, kc4 = lane >> 4;
    #pragma unroll
    for (int mf = 0; mf < 4; ++mf) {
        #pragma unroll
        for (int nf = 0; nf < NF; ++nf) {
            int p = wid * (NF * 16) + nf * 16 + l15;
            ushort4 hb;
            #pragma unroll
            for (int r = 0; r < 4; ++r) {
                int m = mf * 16 + kc4 * 4 + r;
                float v = acc[mf][nf][r] + bias[o0 + m];
                if (act == 1) v = fmaxf(v, 0.f);
                else if (act == 2) v = 0.5f * v * (1.f + erff(v * 0.70710678118f));
                if (of32) of32[((long)(b * Cout) + o0 + m) * P + p0 + p] = v;
                ((unsigned short*)&hb)[r] = f2bf(v);
            }
            if (obf)
                *reinterpret_cast<ushort4*>(
                    &obf[(long)(b * P + p0 + p) * Cout + o0 + mf * 16 + kc4 * 4]) = hb;
        }
    }
}

// ---------------- ConvTranspose2d(k=4,s=2,p=1) via MFMA parity decomposition ----------------
__global__ __launch_bounds__(256) void convt_mfma(
    const unsigned short* __restrict__ xbf, const unsigned short* __restrict__ wp,
    const float* __restrict__ bias, const float* __restrict__ g,
    const float* __restrict__ be, const float* __restrict__ mu,
    const float* __restrict__ va, const unsigned short* __restrict__ resbf,
    float* __restrict__ of32, unsigned short* __restrict__ obf,
    int Cin, int Cout, int Hin, int Win, int TR, int cshift, int OCtot, int cof)
{
    __shared__ __align__(16) unsigned short XS[165 * 32];
    __shared__ __align__(16) unsigned short WS[4 * 64 * 32];
    int t = threadIdx.x;
    int wid = t >> 6, lane = t & 63;
    int z = blockIdx.z;
    int b = z >> 2, par = z & 3;
    int py = par >> 1, px = par & 1;
    int o0 = blockIdx.y * 64;
    int i0 = blockIdx.x * TR;
    int CW = Win, CW1 = CW + 1;
    int npatch = (TR + 1) * CW1;
    int Pin = Hin * Win, Pout = 4 * Hin * Win;
    const unsigned short* xb = xbf + (long)b * Pin * Cin;
    int chunks = Cin >> 5;
    int l15 = lane & 15, kc = lane >> 4;

    f32x4 acc[4][2] = {};

    for (int cc = 0; cc < chunks; ++cc) {
        __syncthreads();
        for (int idx = t; idx < npatch * 4; idx += 256) {
            int pp = idx >> 2, ql = idx & 3;
            int qs = ql ^ ((pp >> 1) & 3);
            int a = pp / CW1, bcol = pp - a * CW1;
            int iy = i0 - (1 - py) + a;
            int ix = bcol - (1 - px);
            u16x8 v = {};
            if (iy >= 0 && iy < Hin && ix >= 0 && ix < Win)
                v = *reinterpret_cast<const u16x8*>(
                    &xb[(long)(iy * Win + ix) * Cin + cc * 32 + qs * 8]);
            *reinterpret_cast<u16x8*>(&XS[pp * 32 + ql * 8]) = v;
        }
        {
            int m = t >> 2, q = t & 3;
            int chq = q ^ ((m >> 1) & 3);
            #pragma unroll
            for (int tap = 0; tap < 4; ++tap) {
                u16x8 v = *reinterpret_cast<const u16x8*>(
                    &wp[((long)((par * 4 + tap) * Cout + o0 + m)) * Cin + cc * 32 + q * 8]);
                *reinterpret_cast<u16x8*>(&WS[tap * 2048 + m * 32 + chq * 8]) = v;
            }
        }
        __syncthreads();

        #pragma unroll
        for (int tap = 0; tap < 4; ++tap) {
            int u = tap >> 1, v = tap & 1;
            bf16x8 af[4], bfr[2];
            #pragma unroll
            for (int mf = 0; mf < 4; ++mf) {
                int row = mf * 16 + l15;
                int ch = kc ^ ((row >> 1) & 3);
                af[mf] = *reinterpret_cast<const bf16x8*>(&WS[tap * 2048 + row * 32 + ch * 8]);
            }
            #pragma unroll
            for (int nf = 0; nf < 2; ++nf) {
                int n = wid * 32 + nf * 16 + l15;
                int rn = n >> cshift, cn = n & (CW - 1);
                int pp = (rn + u) * CW1 + cn + v;
                int ch = kc ^ ((pp >> 1) & 3);
                bfr[nf] = *reinterpret_cast<const bf16x8*>(&XS[pp * 32 + ch * 8]);
            }
            #pragma unroll
            for (int mf = 0; mf < 4; ++mf)
                #pragma unroll
                for (int nf = 0; nf < 2; ++nf)
                    acc[mf][nf] = __builtin_amdgcn_mfma_f32_16x16x32_bf16(
                        af[mf], bfr[nf], acc[mf][nf], 0, 0, 0);
        }
    }

    int kc4 = lane >> 4;
    #pragma unroll
    for (int nf = 0; nf < 2; ++nf) {
        int n = wid * 32 + nf * 16 + l15;
        int rn = n >> cshift, cn = n & (CW - 1);
        int y = 2 * (i0 + rn) + py;
        int xx = 2 * cn + px;
        int pout = y * 2 * Win + xx;
        #pragma unroll
        for (int mf = 0; mf < 4; ++mf) {
            ushort4 hb;
            #pragma unroll
            for (int r = 0; r < 4; ++r) {
                int m = mf * 16 + kc4 * 4 + r;
                int o = o0 + m;
                float s = g[o] * rsqrtf(va[o] + EPSV);
                float v = (acc[mf][nf][r] + bias[o]) * s + (be[o] - mu[o] * s);
                if (resbf) v += bf2f(resbf[(long)(b * Pout + pout) * 256 + o]);
                if (of32) of32[((long)(b * Cout) + o) * Pout + pout] = v;
                ((unsigned short*)&hb)[r] = f2bf(v);
            }
            if (obf)
                *reinterpret_cast<ushort4*>(
                    &obf[(long)(b * Pout + pout) * OCtot + cof + o0 + mf * 16 + kc4 * 4]) = hb;
        }
    }
}

// ---------------- fused lift_net: 1024 thr = 64 px x 16 oc-groups, scalar weights ----------------
__global__ __launch_bounds__(1024) void lift_net_kernel(
    const float* __restrict__ xA, const float* __restrict__ xB,
    const float* __restrict__ oA, const float* __restrict__ oB,
    float* __restrict__ uA, float* __restrict__ uB,
    int x_sB, int x_sC, int x_sR, int x_sA,
    int o_sB, int o_sC, int o_sR, int o_sA,
    int u_sB, int u_sC, int u_sR, int u_sA,
    const float* __restrict__ w1, const float* __restrict__ b1,
    const float* __restrict__ w2, const float* __restrict__ b2,
    int R, int L, int lsh, float sign,
    unsigned short* __restrict__ obf, int Pb, int OCb, int cofA, int cofB)
{
    __shared__ float xsm[4864];
    __shared__ float hsm[8192];
    int t = threadIdx.x;
    int g = t & 63, ocg = t >> 6;
    int b = blockIdx.z;
    int sel = blockIdx.y;
    const float* xin = sel ? xB : xA;
    const float* oth = sel ? oB : oA;
    float* outp = sel ? uB : uA;
    int cofb = sel ? cofB : cofA;
    int rpb = 64 >> lsh;
    int row0 = blockIdx.x * rpb;
    int Lp = L + 3;
    int total = 64 * rpb * Lp;
    for (int idx = t; idx < total; idx += 1024) {
        int c = idx / (rpb * Lp);
        int rem = idx - c * rpb * Lp;
        int rr_l = rem / Lp;
        int q = rem - rr_l * Lp;
        int s = q - 2;
        s = (s < 0) ? -s : s;
        if (s >= L) s = 2 * L - 2 - s;
        xsm[idx] = xin[b * x_sB + c * x_sC + (row0 + rr_l) * x_sR + s * x_sA];
    }
    __syncthreads();

    int ocgu = __builtin_amdgcn_readfirstlane(ocg);
    int rl = g >> lsh, jl = g & (L - 1);
    const float* w1u = w1 + ocgu * 8 * 256;
    float acc1[8] = {};
    for (int c = 0; c < 64; ++c) {
        const float* xr = &xsm[(c * rpb + rl) * Lp + jl];
        float x0 = xr[0], x1 = xr[1], x2 = xr[2], x3 = xr[3];
        const float* wc = w1u + c * 4;
        #pragma unroll
        for (int k = 0; k < 8; ++k) {
            const float* wr = wc + k * 256;
            acc1[k] += wr[0] * x0 + wr[1] * x1 + wr[2] * x2 + wr[3] * x3;
        }
    }
    #pragma unroll
    for (int k = 0; k < 8; ++k) {
        int oc = ocgu * 8 + k;
        hsm[oc * 64 + g] = fmaxf(acc1[k] + b1[oc], 0.f);
    }
    __syncthreads();

    const float* w2u = w2 + ocgu * 4 * 128;
    float acc2[4] = {};
    for (int h4 = 0; h4 < 32; ++h4) {
        float hv0 = hsm[(h4 * 4 + 0) * 64 + g];
        float hv1 = hsm[(h4 * 4 + 1) * 64 + g];
        float hv2 = hsm[(h4 * 4 + 2) * 64 + g];
        float hv3 = hsm[(h4 * 4 + 3) * 64 + g];
        #pragma unroll
        for (int kk = 0; kk < 4; ++kk) {
            const float* wr = w2u + kk * 128 + h4 * 4;
            acc2[kk] += wr[0] * hv0 + wr[1] * hv1 + wr[2] * hv2 + wr[3] * hv3;
        }
    }
    int rg = row0 + rl;
    int p = rg * u_sR + jl * u_sA;
    #pragma unroll
    for (int kk = 0; kk < 4; ++kk) {
        int o = ocgu * 4 + kk;
        float v = oth[b * o_sB + o * o_sC + rg * o_sR + jl * o_sA]
                + sign * tanhf(acc2[kk] + b2[o]);
        outp[b * u_sB + o * u_sC + p] = v;
        if (obf) obf[(long)(b * Pb + p) * OCb + cofb + o] = f2bf(v);
    }
}

// ---------------- fused dw3x3 + relu + dw3x3 + scale + inflate gather + residual ----------------
__global__ __launch_bounds__(256) void dw_fused_kernel(
    const float* __restrict__ r2, const float* __restrict__ w1, const float* __restrict__ b1,
    const float* __restrict__ w2, const float* __restrict__ b2v,
    const float* __restrict__ scw, const float* __restrict__ tok,
    const int* __restrict__ idx, float* __restrict__ out)
{
    __shared__ float s0[64][68];
    __shared__ float s1[64][68];
    __shared__ float s2[4096];
    int bc = blockIdx.x;
    int c = bc & 255;
    int t = threadIdx.x;
    const float* xp = r2 + (long)bc * 4096;
    for (int i = t; i < 4096; i += 256) s0[i >> 6][i & 63] = xp[i];
    float wa[9], wb[9];
    #pragma unroll
    for (int k = 0; k < 9; ++k) { wa[k] = w1[c * 9 + k]; wb[k] = w2[c * 9 + k]; }
    float ba = b1[c], bb = b2v[c], sc = scw[c];
    __syncthreads();
    for (int i = t; i < 4096; i += 256) {
        int y = i >> 6, x = i & 63;
        float a = ba;
        #pragma unroll
        for (int ky = 0; ky < 3; ++ky) {
            int yy = y + ky - 1;
            if (yy < 0 || yy > 63) continue;
            #pragma unroll
            for (int kx = 0; kx < 3; ++kx) {
                int xx = x + kx - 1;
                if (xx < 0 || xx > 63) continue;
                a += wa[ky * 3 + kx] * s0[yy][xx];
            }
        }
        s1[y][x] = fmaxf(a, 0.f);
    }
    __syncthreads();
    for (int i = t; i < 4096; i += 256) {
        int y = i >> 6, x = i & 63;
        float a = bb;
        #pragma unroll
        for (int ky = 0; ky < 3; ++ky) {
            int yy = y + ky - 1;
            if (yy < 0 || yy > 63) continue;
            #pragma unroll
            for (int kx = 0; kx < 3; ++kx) {
                int xx = x + kx - 1;
                if (xx < 0 || xx > 63) continue;
                a += wb[ky * 3 + kx] * s1[yy][xx];
            }
        }
        s2[i] = a * sc;
    }
    __syncthreads();
    long base = (long)bc << 13;
    const int4* ip = (const int4*)(idx + base);
    const float4* tp = (const float4*)(tok + base);
    float4* op = (float4*)(out + base);
    for (int i = t; i < 2048; i += 256) {
        int4 iv = ip[i];
        float4 tv = tp[i];
        float4 o;
        o.x = tv.x + s2[iv.x];
        o.y = tv.y + s2[iv.y];
        o.z = tv.z + s2[iv.z];
        o.w = tv.w + s2[iv.w];
        op[i] = o;
    }
}

extern "C" void kernel_launch(void* const* d_in, const int* in_sizes, int n_in,
                              void* d_out, int out_size, void* d_ws, size_t ws_size,
                              hipStream_t stream)
{
    const float* tokens = (const float*)d_in[0];
    const float* fm     = (const float*)d_in[1];
    const int*   infl   = (const int*)d_in[2];
    const float* bng = (const float*)d_in[3];
    const float* bnb = (const float*)d_in[4];
    const float* bnm = (const float*)d_in[5];
    const float* bnv = (const float*)d_in[6];
    const float* red_w = (const float*)d_in[7];
    const float* red_b = (const float*)d_in[8];
    const float* lw1 = (const float*)d_in[9];
    const float* lb1 = (const float*)d_in[10];
    const float* lw2 = (const float*)d_in[11];
    const float* lb2 = (const float*)d_in[12];
    const float* f2w1 = (const float*)d_in[13];
    const float* f2b1 = (const float*)d_in[14];
    const float* f2w2 = (const float*)d_in[15];
    const float* f2b2 = (const float*)d_in[16];
    const float* ct2w = (const float*)d_in[17];
    const float* ct2b = (const float*)d_in[18];
    const float* bn2g = (const float*)d_in[19];
    const float* bn2b = (const float*)d_in[20];
    const float* bn2m = (const float*)d_in[21];
    const float* bn2v = (const float*)d_in[22];
    const float* f1w1 = (const float*)d_in[23];
    const float* f1b1 = (const float*)d_in[24];
    const float* f1w2 = (const float*)d_in[25];
    const float* f1b2 = (const float*)d_in[26];
    const float* ct1w = (const float*)d_in[27];
    const float* ct1b = (const float*)d_in[28];
    const float* bn1g = (const float*)d_in[29];
    const float* bn1b = (const float*)d_in[30];
    const float* bn1m = (const float*)d_in[31];
    const float* bn1v = (const float*)d_in[32];
    const float* dw1w = (const float*)d_in[33];
    const float* dw1b = (const float*)d_in[34];
    const float* dw2w = (const float*)d_in[35];
    const float* dw2b = (const float*)d_in[36];
    const float* scw  = (const float*)d_in[37];

    float* ws = (float*)d_ws;
    unsigned short* Abf = (unsigned short*)ws;                    // 2,097,152 fl
    float* part  = ws + 2097152;                                  // 4 x 2,097,152 fl
    unsigned short* rgrid_bf = (unsigned short*)(ws + 10485760);  // 1,048,576 fl
    float* rr    = ws + 11534336;   // 524,288
    float* c1    = ws + 12058624;   // 262,144
    float* d1    = ws + 12320768;   // 262,144
    float* c2    = ws + 12582912;   // 65,536
    float* d2    = ws + 12648448;   // 65,536
    float* x2    = ws + 12713984;   // 131,072
    unsigned short* x2_bf  = (unsigned short*)(ws + 12845056);    // 65,536 fl
    float* x1    = ws + 12910592;   // 786,432
    unsigned short* x1_bf  = (unsigned short*)(ws + 13697024);    // 393,216 fl
    unsigned short* g2_bf  = (unsigned short*)(ws + 14090240);    // 65,536 fl
    unsigned short* y2p_bf = (unsigned short*)(ws + 14155776);    // 65,536 fl
    unsigned short* g1_bf  = (unsigned short*)(ws + 14221312);    // 262,144 fl
    unsigned short* y1p_bf = (unsigned short*)(ws + 14483456);    // 262,144 fl
    unsigned short* wp2    = (unsigned short*)(ws + 14745600);    // 262,144 fl
    unsigned short* wp1    = (unsigned short*)(ws + 15007744);    // 524,288 fl
    float* r2 = ws + 15532032;      // 2,097,152

    // 1. prep: BN->bf16 + both weight packs (one launch)
    prep_kernel<<<4864, 256, 0, stream>>>((const float4*)tokens, (ushort4*)Abf,
                                          bng, bnb, bnm, bnv, ct1w, wp1, ct2w, wp2);
    // 2. flatten einsum + add4/transpose
    flatten_gemm_mfma<<<dim3(64, 1, 8), 256, 0, stream>>>(Abf, fm, part);
    add4_t_kernel<<<dim3(64, 4, 2), 256, 0, stream>>>(part, rgrid_bf);
    // 3. reduce 1x1 (256->64)
    conv1x1_mfma<2><<<dim3(32, 1, 2), 256, 0, stream>>>(rgrid_bf, red_w, red_b,
                                                        rr, (unsigned short*)nullptr,
                                                        256, 64, 4096, 0);

    auto lift2 = [&](const float* xA, const float* xB, const float* oA, const float* oB,
                     float* uA, float* uB,
                     int xsB, int xsC, int xsR, int xsA,
                     int osB, int osC, int osR, int osA,
                     int usB, int usC, int usR, int usA,
                     int lvl, int sch, int net, int R, int L, float sign,
                     unsigned short* obf, int Pb, int OCb, int cofA, int cofB, int nsel) {
        int widx = (lvl * 2 + sch) * 2 + net;
        int lsh = (L == 32) ? 5 : 4;
        lift_net_kernel<<<dim3(R * L / 64, nsel, 2), 1024, 0, stream>>>(
            xA, xB, oA, oB, uA, uB,
            xsB, xsC, xsR, xsA, osB, osC, osR, osA, usB, usC, usR, usA,
            lw1 + widx * 32768, lb1 + widx * 128, lw2 + widx * 8192, lb2 + widx * 64,
            R, L, lsh, sign, obf, Pb, OCb, cofA, cofB);
    };

    // ---- stage 1: L1 horizontal P -> d1 ----
    lift2(rr, rr, rr + 1, rr + 1, d1, d1,
          262144, 4096, 64, 2,  262144, 4096, 64, 2,  131072, 2048, 32, 1,
          0, 0, 0, 64, 32, -1.f, nullptr, 0, 0, 0, 0, 1);
    // ---- stage 2: L1 horizontal U -> c1 ----
    lift2(d1, d1, rr, rr, c1, c1,
          131072, 2048, 32, 1,  262144, 4096, 64, 2,  131072, 2048, 32, 1,
          0, 0, 1, 64, 32, +1.f, nullptr, 0, 0, 0, 0, 1);
    // ---- stage 3: L1 vertical P pair ----
    lift2(c1, d1, c1 + 32, d1 + 32, x1 + 65536, x1 + 196608,
          131072, 2048, 1, 64,  131072, 2048, 1, 64,  393216, 1024, 1, 32,
          0, 1, 0, 32, 32, -1.f, x1_bf, 1024, 384, 64, 192, 2);
    // ---- stage 4: L1 vertical U pair ----
    lift2(x1 + 65536, x1 + 196608, c1, d1, x1, x1 + 131072,
          393216, 1024, 1, 32,  131072, 2048, 1, 64,  393216, 1024, 1, 32,
          0, 1, 1, 32, 32, +1.f, x1_bf, 1024, 384, 0, 128, 2);
    // ---- stage 5: L2 horizontal P on LL1 -> d2 ----
    lift2(x1, x1, x1 + 1, x1 + 1, d2, d2,
          393216, 1024, 32, 2,  393216, 1024, 32, 2,  65536, 512, 16, 1,
          1, 0, 0, 32, 16, -1.f, nullptr, 0, 0, 0, 0, 1);
    // ---- stage 6: L2 horizontal U -> c2 ----
    lift2(d2, d2, x1, x1, c2, c2,
          65536, 512, 16, 1,  393216, 1024, 32, 2,  65536, 512, 16, 1,
          1, 0, 1, 32, 16, +1.f, nullptr, 0, 0, 0, 0, 1);
    // ---- stage 7: L2 vertical P pair ----
    lift2(c2, d2, c2 + 16, d2 + 16, x2 + 16384, x2 + 49152,
          65536, 512, 1, 32,  65536, 512, 1, 32,  65536, 256, 1, 16,
          1, 1, 0, 16, 16, -1.f, x2_bf, 256, 256, 64, 192, 2);
    // ---- stage 8: L2 vertical U pair ----
    lift2(x2 + 16384, x2 + 49152, c2, d2, x2, x2 + 32768,
          65536, 256, 1, 16,  65536, 512, 1, 32,  65536, 256, 1, 16,
          1, 1, 1, 16, 16, +1.f, x2_bf, 256, 256, 0, 128, 2);

    // ---- ff2 (bf16 chain) + ct2 -> x1_bf ch 256..383 ----
    conv1x1_mfma<1><<<dim3(4, 4, 2), 256, 0, stream>>>(x2_bf, f2w1, f2b1,
        (float*)nullptr, g2_bf, 256, 256, 256, 2);
    conv1x1_mfma<1><<<dim3(4, 4, 2), 256, 0, stream>>>(g2_bf, f2w2, f2b2,
        (float*)nullptr, y2p_bf, 256, 256, 256, 0);
    convt_mfma<<<dim3(2, 2, 8), 256, 0, stream>>>(y2p_bf, wp2, ct2b,
        bn2g, bn2b, bn2m, bn2v, (const unsigned short*)nullptr,
        (float*)nullptr, x1_bf, 256, 128, 16, 16, 8, 4, 384, 256);

    // ---- ff1 + ct1 (+res rgrid_bf) -> r2 f32 ----
    conv1x1_mfma<2><<<dim3(8, 4, 2), 256, 0, stream>>>(x1_bf, f1w1, f1b1,
        (float*)nullptr, g1_bf, 384, 256, 1024, 2);
    conv1x1_mfma<2><<<dim3(8, 4, 2), 256, 0, stream>>>(g1_bf, f1w2, f1b2,
        (float*)nullptr, y1p_bf, 256, 256, 1024, 0);
    convt_mfma<<<dim3(8, 4, 8), 256, 0, stream>>>(y1p_bf, wp1, ct1b,
        bn1g, bn1b, bn1m, bn1v, rgrid_bf,
        r2, (unsigned short*)nullptr, 256, 256, 32, 32, 4, 5, 0, 0);

    // ---- fused depthwise x2 + scale + gather + residual ----
    dw_fused_kernel<<<512, 256, 0, stream>>>(r2, dw1w, dw1b, dw2w, dw2b, scw,
                                             tokens, infl, (float*)d_out);
}